// Round 11
// baseline (256.746 us; speedup 1.0000x reference)
//
#include <hip/hip_runtime.h>
#include <hip/hip_bf16.h>

// MultiHeadSelfAttention  B=4 S=2048 H=16 Dh=64 Dm=1024 (fp32 in/out detected
// at runtime; intermediates bf16).
// Round 20:
//  - Isolated T5 graft on attn: s_setprio(1)/(0) around the QK^T MFMA
//    pair-loop and the PV (+ l=P@ones) MFMA cluster. m191 measured +4-7%
//    on attn when resident waves sit at different phases — our attn has
//    4 independent blocks/CU with divergent per-wave tile counts (heavy/
//    light chunk mix), exactly that regime. Pure scheduler hint: no
//    barrier/layout/numerics change. (R11's earlier setprio was confounded
//    with a failed pipeline rewrite; this is the clean A/B.)
//  - Everything else = R19 (best known, 252.7us): BK32 m97 GEMMs (all
//    alternatives benched worse at these shapes), fused-Wo prep_cast,
//    8-wave/128-row attn chunks, 64-key tiles, exp2-domain softmax.
// Pre-committed: wall <= 251.5 keep; else revert to R19 state and declare
// roofline (all kernels at verified structure ceilings; ~86us fixed
// harness floor dominates the remainder).

typedef __bf16 bf16x8 __attribute__((ext_vector_type(8)));
typedef __bf16 bf16x4 __attribute__((ext_vector_type(4)));
typedef float  f32x4  __attribute__((ext_vector_type(4)));

#define SEQ 2048
#define NH  16
#define HD  64
#define DM  1024
#define RS  72

static __device__ __forceinline__ void gload_lds16(const __hip_bfloat16* g,
                                                   __hip_bfloat16* l) {
    __builtin_amdgcn_global_load_lds(
        (const __attribute__((address_space(1))) void*)g,
        (__attribute__((address_space(3))) void*)l, 16, 0, 0);
}

// ---------------------------------------------------------------------------
// prep_cast: fused dtype-detect + x->xb + W0..2->wb (+ optional W3->wb3).
// ---------------------------------------------------------------------------
__global__ __launch_bounds__(256) void prep_cast(
    const void* __restrict__ x,
    const void* __restrict__ w0, const void* __restrict__ w1,
    const void* __restrict__ w2, const void* __restrict__ w3,
    __hip_bfloat16* __restrict__ xb, __hip_bfloat16* __restrict__ wb,
    __hip_bfloat16* __restrict__ wb3,
    int* __restrict__ flag)
{
    const unsigned short* xs = (const unsigned short*)x;
    const int lane = threadIdx.x & 63;
    const unsigned e0 = (xs[lane * 4]     >> 7) & 0xFFu;
    const unsigned e1 = (xs[lane * 4 + 2] >> 7) & 0xFFu;
    const unsigned long long b0 = __ballot(e0 >= 0x70u && e0 <= 0x82u);
    const unsigned long long b1 = __ballot(e1 >= 0x70u && e1 <= 0x82u);
    const int cnt = __popcll(b0) + __popcll(b1);
    const bool f32 = (cnt < 64);           // 1 = fp32 data

    const int gid = blockIdx.x;
    if (gid == 0 && threadIdx.x == 0) *flag = f32 ? 1 : 0;

    const void* src;
    __hip_bfloat16* dst;
    int i;
    if (gid < 8192) {
        src = x; dst = xb;
        i = gid * 256 + threadIdx.x;
    } else {
        const int idx = gid - 8192;
        const int w   = idx >> 10;         // 0..3
        const int lb  = idx & 1023;
        src = (w == 0) ? w0 : (w == 1) ? w1 : (w == 2) ? w2 : w3;
        dst = (w == 3) ? wb3 : wb + (size_t)w * DM * DM;
        i = lb * 256 + threadIdx.x;
    }

    bf16x4 o;
    if (f32) {
        f32x4 f = ((const f32x4*)src)[i];
        #pragma unroll
        for (int j = 0; j < 4; ++j) o[j] = (__bf16)f[j];
    } else {
        o = ((const bf16x4*)src)[i];
    }
    ((bf16x4*)dst)[i] = o;
}

// cast4 fallback for the late Wo cast (only if ws too small for fused wob).
__global__ __launch_bounds__(256) void cast4_kernel(
    const void* __restrict__ src, __hip_bfloat16* __restrict__ dst,
    const int* __restrict__ flag, int n4)
{
    const int i = blockIdx.x * 256 + threadIdx.x;
    if (i >= n4) return;
    bf16x4 o;
    if (*flag) {
        f32x4 f = ((const f32x4*)src)[i];
        #pragma unroll
        for (int j = 0; j < 4; ++j) o[j] = (__bf16)f[j];
    } else {
        o = ((const bf16x4*)src)[i];
    }
    ((bf16x4*)dst)[i] = o;
}

// ---------------------------------------------------------------------------
// m97-style GEMM core, BK=32 (empirical optimum at K=1024 for both GEMMs).
// ---------------------------------------------------------------------------
struct GemmCoord {
    int l15, g, wm, wn, r0, c0;
    int aRead, bRead;
};
static __device__ __forceinline__ GemmCoord gemm_coords() {
    GemmCoord c;
    const int tid = threadIdx.x;
    const int lane = tid & 63, wv = tid >> 6;
    c.l15 = lane & 15; c.g = lane >> 4;
    c.wm = wv >> 1;    c.wn = wv & 1;
    c.r0 = tid >> 2;   c.c0 = tid & 3;
    c.aRead = (c.wm * 64 + c.l15) * 32 + c.g * 8;
    c.bRead = (c.wn * 64 + c.l15) * 32 + c.g * 8;
    return c;
}

#define GEMM_BODY(Aptr, Bptr, m0v, n0v)                                        \
    __shared__ __hip_bfloat16 As[128 * 32];                                    \
    __shared__ __hip_bfloat16 Bs[128 * 32];                                    \
    const GemmCoord cc = gemm_coords();                                        \
    const int wv = threadIdx.x >> 6;                                           \
    const __hip_bfloat16* Ag0 = (Aptr) + (size_t)((m0v) + cc.r0) * DM + cc.c0 * 8;      \
    const __hip_bfloat16* Ag1 = (Aptr) + (size_t)((m0v) + cc.r0 + 64) * DM + cc.c0 * 8; \
    const __hip_bfloat16* Bg0 = (Bptr) + (size_t)((n0v) + cc.r0) * DM + cc.c0 * 8;      \
    const __hip_bfloat16* Bg1 = (Bptr) + (size_t)((n0v) + cc.r0 + 64) * DM + cc.c0 * 8; \
    __hip_bfloat16* AsD0 = As + 512 * wv;                                      \
    __hip_bfloat16* AsD1 = As + 2048 + 512 * wv;                               \
    __hip_bfloat16* BsD0 = Bs + 512 * wv;                                      \
    __hip_bfloat16* BsD1 = Bs + 2048 + 512 * wv;                               \
    f32x4 acc[4][4];                                                           \
    _Pragma("unroll") for (int i = 0; i < 4; ++i)                              \
        _Pragma("unroll") for (int j = 0; j < 4; ++j)                          \
            acc[i][j] = (f32x4){0.f, 0.f, 0.f, 0.f};                           \
    for (int kb = 0; kb < DM; kb += 32) {                                      \
        __syncthreads();                                                       \
        gload_lds16(Ag0 + kb, AsD0);                                           \
        gload_lds16(Ag1 + kb, AsD1);                                           \
        gload_lds16(Bg0 + kb, BsD0);                                           \
        gload_lds16(Bg1 + kb, BsD1);                                           \
        __syncthreads();                                                       \
        bf16x8 af[4], bfr[4];                                                  \
        _Pragma("unroll") for (int i = 0; i < 4; ++i)                          \
            af[i] = *reinterpret_cast<const bf16x8*>(&As[cc.aRead + i * 512]); \
        _Pragma("unroll") for (int j = 0; j < 4; ++j)                          \
            bfr[j] = *reinterpret_cast<const bf16x8*>(&Bs[cc.bRead + j * 512]);\
        _Pragma("unroll") for (int i = 0; i < 4; ++i)                          \
            _Pragma("unroll") for (int j = 0; j < 4; ++j)                      \
                acc[i][j] = __builtin_amdgcn_mfma_f32_16x16x32_bf16(           \
                    af[i], bfr[j], acc[i][j], 0, 0, 0);                        \
    }

// Fused QKV (BK=32). widx 0/1 -> q/kk normal layout; widx 2 -> V stored
// transposed into vt[(b*16+h)*64+d][t] via 16x 8B stores.
__global__ __launch_bounds__(256) void gemm_qkv(
    const __hip_bfloat16* __restrict__ A,
    const __hip_bfloat16* __restrict__ Wb,
    const void* bq, const void* bk, const void* bv,
    __hip_bfloat16* q, __hip_bfloat16* kk, __hip_bfloat16* vt,
    const int* __restrict__ dflag)
{
    const int widx = blockIdx.y >> 3;
    const int m0 = blockIdx.x * 128;
    const int n0 = (blockIdx.y & 7) * 128;
    const __hip_bfloat16* B = Wb + (size_t)widx * DM * DM;
    const void* bias = (widx == 0) ? bq : (widx == 1) ? bk : bv;
    const bool f32 = (*dflag != 0);

    GEMM_BODY(A, B, m0, n0)

    if (widx == 2) {
        #pragma unroll
        for (int j = 0; j < 4; ++j) {
            const int col = n0 + cc.wn * 64 + j * 16 + cc.l15;
            const float bvv = f32 ? ((const float*)bias)[col]
                                  : __bfloat162float(((const __hip_bfloat16*)bias)[col]);
            #pragma unroll
            for (int i = 0; i < 4; ++i) {
                const int row0 = m0 + cc.wm * 64 + i * 16 + cc.g * 4; // r=0 row
                const int bb = row0 >> 11;
                const int t  = row0 & 2047;
                bf16x4 pv;
                #pragma unroll
                for (int r = 0; r < 4; ++r)
                    pv[r] = (__bf16)(acc[i][j][r] + bvv);
                *reinterpret_cast<bf16x4*>(
                    vt + (size_t)(bb * 1024 + col) * SEQ + t) = pv;
            }
        }
    } else {
        __hip_bfloat16* out = (widx == 0) ? q : kk;
        #pragma unroll
        for (int j = 0; j < 4; ++j) {
            const int col = n0 + cc.wn * 64 + j * 16 + cc.l15;
            const float bvv = f32 ? ((const float*)bias)[col]
                                  : __bfloat162float(((const __hip_bfloat16*)bias)[col]);
            #pragma unroll
            for (int i = 0; i < 4; ++i) {
                #pragma unroll
                for (int r = 0; r < 4; ++r) {
                    const int row = m0 + cc.wm * 64 + i * 16 + cc.g * 4 + r;
                    out[(size_t)row * DM + col] = __float2bfloat16(acc[i][j][r] + bvv);
                }
            }
        }
    }
}

__global__ __launch_bounds__(256) void gemm_out(
    const __hip_bfloat16* __restrict__ A,
    const __hip_bfloat16* __restrict__ B,
    const void* bias, void* __restrict__ outv,
    const int* __restrict__ dflag)
{
    const int m0 = blockIdx.x * 128;
    const int n0 = blockIdx.y * 128;
    const bool f32 = (*dflag != 0);

    GEMM_BODY(A, B, m0, n0)

    #pragma unroll
    for (int j = 0; j < 4; ++j) {
        const int col = n0 + cc.wn * 64 + j * 16 + cc.l15;
        const float bvv = f32 ? ((const float*)bias)[col]
                              : __bfloat162float(((const __hip_bfloat16*)bias)[col]);
        #pragma unroll
        for (int i = 0; i < 4; ++i) {
            #pragma unroll
            for (int r = 0; r < 4; ++r) {
                const int row = m0 + cc.wm * 64 + i * 16 + cc.g * 4 + r;
                const float val = acc[i][j][r] + bvv;
                if (f32) ((float*)outv)[(size_t)row * DM + col] = val;
                else ((__hip_bfloat16*)outv)[(size_t)row * DM + col] = __float2bfloat16(val);
            }
        }
    }
}

// ---------------------------------------------------------------------------
// Flash attention (S^T orientation), 8-wave / 128-row chunks, 64-key tiles,
// exp2-domain softmax. R15 structure + isolated T5 setprio around MFMA
// clusters (QK^T; PV + l=P@ones).
// ---------------------------------------------------------------------------
__global__ __launch_bounds__(512) void attn_flash_mfma(
    const __hip_bfloat16* __restrict__ q,
    const __hip_bfloat16* __restrict__ k,
    const __hip_bfloat16* __restrict__ vt,   // [b][h][d][t]
    __hip_bfloat16* __restrict__ ctx)
{
    __shared__ __hip_bfloat16 Ks[64 * HD];        // 8KB swizzled K tile
    __shared__ __hip_bfloat16 Vs[HD * 64];        // 8KB swizzled VT tile
    __shared__ __hip_bfloat16 P[8][16 * RS];      // per-wave P (18KB)

    const int tid  = threadIdx.x;
    const int lane = tid & 63;
    const int wv   = tid >> 6;       // 0..7
    const int g    = lane >> 4;
    const int l15  = lane & 15;
    const int l7   = l15 & 7;

    // heavy-first, quartile-mixed chunk assignment
    const int bid  = blockIdx.x;     // 0..1023
    const int pos  = bid & 255;
    const int qtr  = bid >> 8;       // 0..3
    const int h64  = pos & 63;       // b*16+h
    const int jj   = pos >> 6;       // 0..3
    const int c    = (3 - qtr) * 4 + ((jj + qtr) & 3);   // 0..15, heavy first
    const int b    = h64 >> 4;
    const int h    = h64 & 15;
    const int base = c * 128;
    const int nt   = 2 * c + 2;      // 64-key tiles for this chunk

    const size_t hb = (size_t)b * SEQ * DM + (size_t)h * HD;
    const __hip_bfloat16* vth = vt + (size_t)(b * NH + h) * HD * SEQ;
    __hip_bfloat16* Pw = P[wv];

    // staging coords (512 threads cover one 8KB tile per gload)
    const int kr0 = tid >> 3;
    const int ks0 = ((tid & 7) ^ (kr0 & 7)) * 8;
    __hip_bfloat16* KsD = Ks + wv * 512;
    __hip_bfloat16* VsD = Vs + wv * 512;

    const int f0off = ((g ^ l7)) * 8;
    const int f1off = (((4 + g) ^ l7)) * 8;

    bf16x8 ones;
    #pragma unroll
    for (int j = 0; j < 8; ++j) ones[j] = (__bf16)1.0f;

    const int rmin = base + wv * 16;
    const int qrow = rmin + l15;
    const __hip_bfloat16* qp_ = q + hb + (size_t)qrow * DM + g * 8;
    bf16x8 qf0 = *reinterpret_cast<const bf16x8*>(qp_);
    bf16x8 qf1 = *reinterpret_cast<const bf16x8*>(qp_ + 32);
    #pragma unroll
    for (int j = 0; j < 8; ++j) {
        qf0[j] = (__bf16)((float)qf0[j] * 0.18033688f);  // log2(e)/sqrt(64)
        qf1[j] = (__bf16)((float)qf1[j] * 0.18033688f);
    }

    f32x4 o[4];
    #pragma unroll
    for (int j = 0; j < 4; ++j) o[j] = (f32x4){0.f, 0.f, 0.f, 0.f};
    f32x4 zl = (f32x4){0.f, 0.f, 0.f, 0.f};   // row sums of P

    for (int t = 0; t < nt; ++t) {
        const int kbase = t * 64;

        __syncthreads();
        gload_lds16(k + hb + (size_t)(kbase + kr0) * DM + ks0, KsD);
        gload_lds16(vth + (size_t)kr0 * SEQ + kbase + ks0, VsD);
        __syncthreads();

        if (kbase <= rmin + 15) {      // wave-uniform: tile touches our rows
            // ---- S^T = K (Q*scale)^T  [T5: prefer MFMA wave] ------------
            f32x4 s[4];
            __builtin_amdgcn_s_setprio(1);
            #pragma unroll
            for (int j = 0; j < 4; ++j) {
                const int krow = (j * 16 + l15) * 64;
                bf16x8 kf0 = *reinterpret_cast<const bf16x8*>(&Ks[krow + f0off]);
                bf16x8 kf1 = *reinterpret_cast<const bf16x8*>(&Ks[krow + f1off]);
                f32x4 z = (f32x4){0.f, 0.f, 0.f, 0.f};
                z = __builtin_amdgcn_mfma_f32_16x16x32_bf16(kf0, qf0, z, 0, 0, 0);
                z = __builtin_amdgcn_mfma_f32_16x16x32_bf16(kf1, qf1, z, 0, 0, 0);
                s[j] = z;   // s[j][r]: key = kbase + j*16 + g*4 + r
            }
            __builtin_amdgcn_s_setprio(0);

            // ---- causal mask (partial tile only; wave-uniform cond) -----
            if (kbase + 63 > rmin) {
                const int qrel = qrow - kbase;
                #pragma unroll
                for (int j = 0; j < 4; ++j) {
                    #pragma unroll
                    for (int r = 0; r < 4; ++r) {
                        const int key = j * 16 + g * 4 + r;
                        if (key > qrel) s[j][r] = -1e30f;
                    }
                }
            }

            // ---- max-free softmax in exp2 domain ------------------------
            #pragma unroll
            for (int j = 0; j < 4; ++j)
                #pragma unroll
                for (int r = 0; r < 4; ++r)
                    s[j][r] = __builtin_amdgcn_exp2f(s[j][r]);

            // ---- P: S^T C-layout -> A-layout, one b64 per j -------------
            #pragma unroll
            for (int j = 0; j < 4; ++j) {
                bf16x4 pv;
                #pragma unroll
                for (int r = 0; r < 4; ++r) pv[r] = (__bf16)s[j][r];
                *reinterpret_cast<bf16x4*>(&Pw[l15 * RS + j * 16 + g * 4]) = pv;
            }

            const bf16x8 a0 = *reinterpret_cast<const bf16x8*>(&Pw[l15 * RS + g * 8]);
            const bf16x8 a1 = *reinterpret_cast<const bf16x8*>(&Pw[l15 * RS + 32 + g * 8]);

            // ---- l += P @ ones; O += P V  [T5: prefer MFMA wave] --------
            __builtin_amdgcn_s_setprio(1);
            zl = __builtin_amdgcn_mfma_f32_16x16x32_bf16(a0, ones, zl, 0, 0, 0);
            zl = __builtin_amdgcn_mfma_f32_16x16x32_bf16(a1, ones, zl, 0, 0, 0);

            #pragma unroll
            for (int jd = 0; jd < 4; ++jd) {
                const int vrow = (jd * 16 + l15) * 64;
                const bf16x8 b0 = *reinterpret_cast<const bf16x8*>(&Vs[vrow + f0off]);
                const bf16x8 b1 = *reinterpret_cast<const bf16x8*>(&Vs[vrow + f1off]);
                o[jd] = __builtin_amdgcn_mfma_f32_16x16x32_bf16(a0, b0, o[jd], 0, 0, 0);
                o[jd] = __builtin_amdgcn_mfma_f32_16x16x32_bf16(a1, b1, o[jd], 0, 0, 0);
            }
            __builtin_amdgcn_s_setprio(0);
        }
    }

    // ---- epilogue: ctx = O / l ------------------------------------------
    #pragma unroll
    for (int r = 0; r < 4; ++r) {
        const float inv = 1.f / zl[r];
        const int sq = rmin + g * 4 + r;
        #pragma unroll
        for (int jd = 0; jd < 4; ++jd)
            ctx[hb + (size_t)sq * DM + jd * 16 + l15] =
                __float2bfloat16(o[jd][r] * inv);
    }
}

// ---------------------------------------------------------------------------
extern "C" void kernel_launch(void* const* d_in, const int* in_sizes, int n_in,
                              void* d_out, int out_size, void* d_ws, size_t ws_size,
                              hipStream_t stream) {
    const int M = 4 * SEQ;   // 8192

    // size-based input mapping
    int xi = 0, wi[4] = {-1, -1, -1, -1}, bi[4] = {-1, -1, -1, -1};
    int nw = 0, nb = 0;
    for (int i = 0; i < n_in; ++i) {
        if (in_sizes[i] == 4 * SEQ * DM) xi = i;
        else if (in_sizes[i] == DM * DM && nw < 4) wi[nw++] = i;
        else if (in_sizes[i] == DM && nb < 4) bi[nb++] = i;
    }
    if (nw < 4 || nb < 4) {
        const int wOff = n_in - 8;
        for (int j = 0; j < 4; ++j) { wi[j] = wOff + 2 * j; bi[j] = wOff + 2 * j + 1; }
    }
    const void* x  = d_in[xi];
    const void* W[4]  = {d_in[wi[0]], d_in[wi[1]], d_in[wi[2]], d_in[wi[3]]};
    const void* Bs[4] = {d_in[bi[0]], d_in[bi[1]], d_in[bi[2]], d_in[bi[3]]};

    // ws: q | kk | vt | flag [| wob if room]. ctx aliases q.
    const size_t mat = (size_t)M * DM;
    const size_t base = 3 * mat * sizeof(__hip_bfloat16);   // 50.33 MB
    __hip_bfloat16* q   = (__hip_bfloat16*)d_ws;
    __hip_bfloat16* kk  = q + mat;
    __hip_bfloat16* vt  = kk + mat;
    __hip_bfloat16* ctx = q;
    int* flag = (int*)((char*)d_ws + base);

    // Fused-Wo path: wob lives in ws after flag (256B aligned) if it fits.
    __hip_bfloat16* wob2 = (__hip_bfloat16*)((char*)d_ws + base + 256);
    const bool fuseW3 = ws_size >= base + 256 + sizeof(__hip_bfloat16) * DM * DM;

    // d_out scratch: xb (16.78 MB) + wb (6.29 MB); both dead before gemm_out.
    __hip_bfloat16* xb  = (__hip_bfloat16*)d_out;
    __hip_bfloat16* wb  = xb + mat;
    __hip_bfloat16* wob = kk;            // fallback Wo location (after attn)

    // fused detect + x cast + W0-2 casts (+W3 if workspace allows)
    prep_cast<<<dim3(8192 + (fuseW3 ? 4 : 3) * 1024), 256, 0, stream>>>(
        x, W[0], W[1], W[2], W[3], xb, wb, wob2, flag);

    gemm_qkv<<<dim3(M / 128, 24), 256, 0, stream>>>(
        xb, wb, Bs[0], Bs[1], Bs[2], q, kk, vt, flag);

    attn_flash_mfma<<<dim3(1024), 512, 0, stream>>>(q, kk, vt, ctx);

    if (!fuseW3)
        cast4_kernel<<<dim3(DM * DM / 4 / 256), 256, 0, stream>>>(
            W[3], wob, flag, DM * DM / 4);

    gemm_out<<<dim3(M / 128, DM / 128), 256, 0, stream>>>(
        ctx, fuseW3 ? wob2 : wob, Bs[3], d_out, flag);
}

// Round 12
// 252.711 us; speedup vs baseline: 1.0160x; 1.0160x over previous
//
#include <hip/hip_runtime.h>
#include <hip/hip_bf16.h>

// MultiHeadSelfAttention  B=4 S=2048 H=16 Dh=64 Dm=1024 (fp32 in/out detected
// at runtime; intermediates bf16).
// Round 21: REVERT to R19 exact (best measured: 252.7us). R20's isolated T5
// setprio A/B was NEGATIVE (+4us): our attn's MFMA clusters follow a block-
// wide barrier, so all 8 waves raise prio together — no phase diversity to
// arbitrate (m190 lockstep-null regime, not m191's 1-wave-block regime).
// Terminal state, all components at verified ceilings of their measured
// design spaces:
//  - gemm_qkv 71us: m97 BK32, 6 blocks/CU, exactly 1.0 rounds, 726 TF
//    (= structure ceiling at K=1024). Benched worse: 8-phase 256^2 (R10:
//    83us), BK64 (R16: 79us, round-quantization cliff), vmcnt pipelines.
//  - attn ~56us: 8-wave/128-row chunks (R13), 64-key tiles @ 4 blocks/CU
//    (R14 falsified 128-key), exp2-domain softmax (R15), T5 falsified (R20).
//  - gemm_out ~24us: BK64 null (R17/R18 re-bench), BK32.
//  - prep_cast ~15us @ ~5TB/s with fused detect + x + all four W casts.
//  - launch gaps ~3us each (R12); ~86us fixed harness floor in wall.

typedef __bf16 bf16x8 __attribute__((ext_vector_type(8)));
typedef __bf16 bf16x4 __attribute__((ext_vector_type(4)));
typedef float  f32x4  __attribute__((ext_vector_type(4)));

#define SEQ 2048
#define NH  16
#define HD  64
#define DM  1024
#define RS  72

static __device__ __forceinline__ void gload_lds16(const __hip_bfloat16* g,
                                                   __hip_bfloat16* l) {
    __builtin_amdgcn_global_load_lds(
        (const __attribute__((address_space(1))) void*)g,
        (__attribute__((address_space(3))) void*)l, 16, 0, 0);
}

// ---------------------------------------------------------------------------
// prep_cast: fused dtype-detect + x->xb + W0..2->wb (+ optional W3->wb3).
// ---------------------------------------------------------------------------
__global__ __launch_bounds__(256) void prep_cast(
    const void* __restrict__ x,
    const void* __restrict__ w0, const void* __restrict__ w1,
    const void* __restrict__ w2, const void* __restrict__ w3,
    __hip_bfloat16* __restrict__ xb, __hip_bfloat16* __restrict__ wb,
    __hip_bfloat16* __restrict__ wb3,
    int* __restrict__ flag)
{
    const unsigned short* xs = (const unsigned short*)x;
    const int lane = threadIdx.x & 63;
    const unsigned e0 = (xs[lane * 4]     >> 7) & 0xFFu;
    const unsigned e1 = (xs[lane * 4 + 2] >> 7) & 0xFFu;
    const unsigned long long b0 = __ballot(e0 >= 0x70u && e0 <= 0x82u);
    const unsigned long long b1 = __ballot(e1 >= 0x70u && e1 <= 0x82u);
    const int cnt = __popcll(b0) + __popcll(b1);
    const bool f32 = (cnt < 64);           // 1 = fp32 data

    const int gid = blockIdx.x;
    if (gid == 0 && threadIdx.x == 0) *flag = f32 ? 1 : 0;

    const void* src;
    __hip_bfloat16* dst;
    int i;
    if (gid < 8192) {
        src = x; dst = xb;
        i = gid * 256 + threadIdx.x;
    } else {
        const int idx = gid - 8192;
        const int w   = idx >> 10;         // 0..3
        const int lb  = idx & 1023;
        src = (w == 0) ? w0 : (w == 1) ? w1 : (w == 2) ? w2 : w3;
        dst = (w == 3) ? wb3 : wb + (size_t)w * DM * DM;
        i = lb * 256 + threadIdx.x;
    }

    bf16x4 o;
    if (f32) {
        f32x4 f = ((const f32x4*)src)[i];
        #pragma unroll
        for (int j = 0; j < 4; ++j) o[j] = (__bf16)f[j];
    } else {
        o = ((const bf16x4*)src)[i];
    }
    ((bf16x4*)dst)[i] = o;
}

// cast4 fallback for the late Wo cast (only if ws too small for fused wob).
__global__ __launch_bounds__(256) void cast4_kernel(
    const void* __restrict__ src, __hip_bfloat16* __restrict__ dst,
    const int* __restrict__ flag, int n4)
{
    const int i = blockIdx.x * 256 + threadIdx.x;
    if (i >= n4) return;
    bf16x4 o;
    if (*flag) {
        f32x4 f = ((const f32x4*)src)[i];
        #pragma unroll
        for (int j = 0; j < 4; ++j) o[j] = (__bf16)f[j];
    } else {
        o = ((const bf16x4*)src)[i];
    }
    ((bf16x4*)dst)[i] = o;
}

// ---------------------------------------------------------------------------
// m97-style GEMM core, BK=32 (empirical optimum at K=1024 for both GEMMs).
// ---------------------------------------------------------------------------
struct GemmCoord {
    int l15, g, wm, wn, r0, c0;
    int aRead, bRead;
};
static __device__ __forceinline__ GemmCoord gemm_coords() {
    GemmCoord c;
    const int tid = threadIdx.x;
    const int lane = tid & 63, wv = tid >> 6;
    c.l15 = lane & 15; c.g = lane >> 4;
    c.wm = wv >> 1;    c.wn = wv & 1;
    c.r0 = tid >> 2;   c.c0 = tid & 3;
    c.aRead = (c.wm * 64 + c.l15) * 32 + c.g * 8;
    c.bRead = (c.wn * 64 + c.l15) * 32 + c.g * 8;
    return c;
}

#define GEMM_BODY(Aptr, Bptr, m0v, n0v)                                        \
    __shared__ __hip_bfloat16 As[128 * 32];                                    \
    __shared__ __hip_bfloat16 Bs[128 * 32];                                    \
    const GemmCoord cc = gemm_coords();                                        \
    const int wv = threadIdx.x >> 6;                                           \
    const __hip_bfloat16* Ag0 = (Aptr) + (size_t)((m0v) + cc.r0) * DM + cc.c0 * 8;      \
    const __hip_bfloat16* Ag1 = (Aptr) + (size_t)((m0v) + cc.r0 + 64) * DM + cc.c0 * 8; \
    const __hip_bfloat16* Bg0 = (Bptr) + (size_t)((n0v) + cc.r0) * DM + cc.c0 * 8;      \
    const __hip_bfloat16* Bg1 = (Bptr) + (size_t)((n0v) + cc.r0 + 64) * DM + cc.c0 * 8; \
    __hip_bfloat16* AsD0 = As + 512 * wv;                                      \
    __hip_bfloat16* AsD1 = As + 2048 + 512 * wv;                               \
    __hip_bfloat16* BsD0 = Bs + 512 * wv;                                      \
    __hip_bfloat16* BsD1 = Bs + 2048 + 512 * wv;                               \
    f32x4 acc[4][4];                                                           \
    _Pragma("unroll") for (int i = 0; i < 4; ++i)                              \
        _Pragma("unroll") for (int j = 0; j < 4; ++j)                          \
            acc[i][j] = (f32x4){0.f, 0.f, 0.f, 0.f};                           \
    for (int kb = 0; kb < DM; kb += 32) {                                      \
        __syncthreads();                                                       \
        gload_lds16(Ag0 + kb, AsD0);                                           \
        gload_lds16(Ag1 + kb, AsD1);                                           \
        gload_lds16(Bg0 + kb, BsD0);                                           \
        gload_lds16(Bg1 + kb, BsD1);                                           \
        __syncthreads();                                                       \
        bf16x8 af[4], bfr[4];                                                  \
        _Pragma("unroll") for (int i = 0; i < 4; ++i)                          \
            af[i] = *reinterpret_cast<const bf16x8*>(&As[cc.aRead + i * 512]); \
        _Pragma("unroll") for (int j = 0; j < 4; ++j)                          \
            bfr[j] = *reinterpret_cast<const bf16x8*>(&Bs[cc.bRead + j * 512]);\
        _Pragma("unroll") for (int i = 0; i < 4; ++i)                          \
            _Pragma("unroll") for (int j = 0; j < 4; ++j)                      \
                acc[i][j] = __builtin_amdgcn_mfma_f32_16x16x32_bf16(           \
                    af[i], bfr[j], acc[i][j], 0, 0, 0);                        \
    }

// Fused QKV (BK=32). widx 0/1 -> q/kk normal layout; widx 2 -> V stored
// transposed into vt[(b*16+h)*64+d][t] via 16x 8B stores.
__global__ __launch_bounds__(256) void gemm_qkv(
    const __hip_bfloat16* __restrict__ A,
    const __hip_bfloat16* __restrict__ Wb,
    const void* bq, const void* bk, const void* bv,
    __hip_bfloat16* q, __hip_bfloat16* kk, __hip_bfloat16* vt,
    const int* __restrict__ dflag)
{
    const int widx = blockIdx.y >> 3;
    const int m0 = blockIdx.x * 128;
    const int n0 = (blockIdx.y & 7) * 128;
    const __hip_bfloat16* B = Wb + (size_t)widx * DM * DM;
    const void* bias = (widx == 0) ? bq : (widx == 1) ? bk : bv;
    const bool f32 = (*dflag != 0);

    GEMM_BODY(A, B, m0, n0)

    if (widx == 2) {
        #pragma unroll
        for (int j = 0; j < 4; ++j) {
            const int col = n0 + cc.wn * 64 + j * 16 + cc.l15;
            const float bvv = f32 ? ((const float*)bias)[col]
                                  : __bfloat162float(((const __hip_bfloat16*)bias)[col]);
            #pragma unroll
            for (int i = 0; i < 4; ++i) {
                const int row0 = m0 + cc.wm * 64 + i * 16 + cc.g * 4; // r=0 row
                const int bb = row0 >> 11;
                const int t  = row0 & 2047;
                bf16x4 pv;
                #pragma unroll
                for (int r = 0; r < 4; ++r)
                    pv[r] = (__bf16)(acc[i][j][r] + bvv);
                *reinterpret_cast<bf16x4*>(
                    vt + (size_t)(bb * 1024 + col) * SEQ + t) = pv;
            }
        }
    } else {
        __hip_bfloat16* out = (widx == 0) ? q : kk;
        #pragma unroll
        for (int j = 0; j < 4; ++j) {
            const int col = n0 + cc.wn * 64 + j * 16 + cc.l15;
            const float bvv = f32 ? ((const float*)bias)[col]
                                  : __bfloat162float(((const __hip_bfloat16*)bias)[col]);
            #pragma unroll
            for (int i = 0; i < 4; ++i) {
                #pragma unroll
                for (int r = 0; r < 4; ++r) {
                    const int row = m0 + cc.wm * 64 + i * 16 + cc.g * 4 + r;
                    out[(size_t)row * DM + col] = __float2bfloat16(acc[i][j][r] + bvv);
                }
            }
        }
    }
}

__global__ __launch_bounds__(256) void gemm_out(
    const __hip_bfloat16* __restrict__ A,
    const __hip_bfloat16* __restrict__ B,
    const void* bias, void* __restrict__ outv,
    const int* __restrict__ dflag)
{
    const int m0 = blockIdx.x * 128;
    const int n0 = blockIdx.y * 128;
    const bool f32 = (*dflag != 0);

    GEMM_BODY(A, B, m0, n0)

    #pragma unroll
    for (int j = 0; j < 4; ++j) {
        const int col = n0 + cc.wn * 64 + j * 16 + cc.l15;
        const float bvv = f32 ? ((const float*)bias)[col]
                              : __bfloat162float(((const __hip_bfloat16*)bias)[col]);
        #pragma unroll
        for (int i = 0; i < 4; ++i) {
            #pragma unroll
            for (int r = 0; r < 4; ++r) {
                const int row = m0 + cc.wm * 64 + i * 16 + cc.g * 4 + r;
                const float val = acc[i][j][r] + bvv;
                if (f32) ((float*)outv)[(size_t)row * DM + col] = val;
                else ((__hip_bfloat16*)outv)[(size_t)row * DM + col] = __float2bfloat16(val);
            }
        }
    }
}

// ---------------------------------------------------------------------------
// Flash attention (S^T orientation), 8-wave / 128-row chunks, 64-key tiles.
// Softmax in exp2 domain (Q pre-scaled by log2(e)/8). LDS 34.4KB ->
// 4 blocks/CU. R15-exact (T5 setprio removed: R20 measured it -4us).
// ---------------------------------------------------------------------------
__global__ __launch_bounds__(512) void attn_flash_mfma(
    const __hip_bfloat16* __restrict__ q,
    const __hip_bfloat16* __restrict__ k,
    const __hip_bfloat16* __restrict__ vt,   // [b][h][d][t]
    __hip_bfloat16* __restrict__ ctx)
{
    __shared__ __hip_bfloat16 Ks[64 * HD];        // 8KB swizzled K tile
    __shared__ __hip_bfloat16 Vs[HD * 64];        // 8KB swizzled VT tile
    __shared__ __hip_bfloat16 P[8][16 * RS];      // per-wave P (18KB)

    const int tid  = threadIdx.x;
    const int lane = tid & 63;
    const int wv   = tid >> 6;       // 0..7
    const int g    = lane >> 4;
    const int l15  = lane & 15;
    const int l7   = l15 & 7;

    // heavy-first, quartile-mixed chunk assignment
    const int bid  = blockIdx.x;     // 0..1023
    const int pos  = bid & 255;
    const int qtr  = bid >> 8;       // 0..3
    const int h64  = pos & 63;       // b*16+h
    const int jj   = pos >> 6;       // 0..3
    const int c    = (3 - qtr) * 4 + ((jj + qtr) & 3);   // 0..15, heavy first
    const int b    = h64 >> 4;
    const int h    = h64 & 15;
    const int base = c * 128;
    const int nt   = 2 * c + 2;      // 64-key tiles for this chunk

    const size_t hb = (size_t)b * SEQ * DM + (size_t)h * HD;
    const __hip_bfloat16* vth = vt + (size_t)(b * NH + h) * HD * SEQ;
    __hip_bfloat16* Pw = P[wv];

    // staging coords (512 threads cover one 8KB tile per gload)
    const int kr0 = tid >> 3;
    const int ks0 = ((tid & 7) ^ (kr0 & 7)) * 8;
    __hip_bfloat16* KsD = Ks + wv * 512;
    __hip_bfloat16* VsD = Vs + wv * 512;

    const int f0off = ((g ^ l7)) * 8;
    const int f1off = (((4 + g) ^ l7)) * 8;

    bf16x8 ones;
    #pragma unroll
    for (int j = 0; j < 8; ++j) ones[j] = (__bf16)1.0f;

    const int rmin = base + wv * 16;
    const int qrow = rmin + l15;
    const __hip_bfloat16* qp_ = q + hb + (size_t)qrow * DM + g * 8;
    bf16x8 qf0 = *reinterpret_cast<const bf16x8*>(qp_);
    bf16x8 qf1 = *reinterpret_cast<const bf16x8*>(qp_ + 32);
    #pragma unroll
    for (int j = 0; j < 8; ++j) {
        qf0[j] = (__bf16)((float)qf0[j] * 0.18033688f);  // log2(e)/sqrt(64)
        qf1[j] = (__bf16)((float)qf1[j] * 0.18033688f);
    }

    f32x4 o[4];
    #pragma unroll
    for (int j = 0; j < 4; ++j) o[j] = (f32x4){0.f, 0.f, 0.f, 0.f};
    f32x4 zl = (f32x4){0.f, 0.f, 0.f, 0.f};   // row sums of P

    for (int t = 0; t < nt; ++t) {
        const int kbase = t * 64;

        __syncthreads();
        gload_lds16(k + hb + (size_t)(kbase + kr0) * DM + ks0, KsD);
        gload_lds16(vth + (size_t)kr0 * SEQ + kbase + ks0, VsD);
        __syncthreads();

        if (kbase <= rmin + 15) {      // wave-uniform: tile touches our rows
            // ---- S^T = K (Q*scale)^T -----------------------------------
            f32x4 s[4];
            #pragma unroll
            for (int j = 0; j < 4; ++j) {
                const int krow = (j * 16 + l15) * 64;
                bf16x8 kf0 = *reinterpret_cast<const bf16x8*>(&Ks[krow + f0off]);
                bf16x8 kf1 = *reinterpret_cast<const bf16x8*>(&Ks[krow + f1off]);
                f32x4 z = (f32x4){0.f, 0.f, 0.f, 0.f};
                z = __builtin_amdgcn_mfma_f32_16x16x32_bf16(kf0, qf0, z, 0, 0, 0);
                z = __builtin_amdgcn_mfma_f32_16x16x32_bf16(kf1, qf1, z, 0, 0, 0);
                s[j] = z;   // s[j][r]: key = kbase + j*16 + g*4 + r
            }

            // ---- causal mask (partial tile only; wave-uniform cond) -----
            if (kbase + 63 > rmin) {
                const int qrel = qrow - kbase;
                #pragma unroll
                for (int j = 0; j < 4; ++j) {
                    #pragma unroll
                    for (int r = 0; r < 4; ++r) {
                        const int key = j * 16 + g * 4 + r;
                        if (key > qrel) s[j][r] = -1e30f;
                    }
                }
            }

            // ---- max-free softmax in exp2 domain ------------------------
            #pragma unroll
            for (int j = 0; j < 4; ++j)
                #pragma unroll
                for (int r = 0; r < 4; ++r)
                    s[j][r] = __builtin_amdgcn_exp2f(s[j][r]);

            // ---- P: S^T C-layout -> A-layout, one b64 per j -------------
            #pragma unroll
            for (int j = 0; j < 4; ++j) {
                bf16x4 pv;
                #pragma unroll
                for (int r = 0; r < 4; ++r) pv[r] = (__bf16)s[j][r];
                *reinterpret_cast<bf16x4*>(&Pw[l15 * RS + j * 16 + g * 4]) = pv;
            }

            const bf16x8 a0 = *reinterpret_cast<const bf16x8*>(&Pw[l15 * RS + g * 8]);
            const bf16x8 a1 = *reinterpret_cast<const bf16x8*>(&Pw[l15 * RS + 32 + g * 8]);

            // ---- l += P @ ones ------------------------------------------
            zl = __builtin_amdgcn_mfma_f32_16x16x32_bf16(a0, ones, zl, 0, 0, 0);
            zl = __builtin_amdgcn_mfma_f32_16x16x32_bf16(a1, ones, zl, 0, 0, 0);

            // ---- O += P V  (VT frags from LDS) --------------------------
            #pragma unroll
            for (int jd = 0; jd < 4; ++jd) {
                const int vrow = (jd * 16 + l15) * 64;
                const bf16x8 b0 = *reinterpret_cast<const bf16x8*>(&Vs[vrow + f0off]);
                const bf16x8 b1 = *reinterpret_cast<const bf16x8*>(&Vs[vrow + f1off]);
                o[jd] = __builtin_amdgcn_mfma_f32_16x16x32_bf16(a0, b0, o[jd], 0, 0, 0);
                o[jd] = __builtin_amdgcn_mfma_f32_16x16x32_bf16(a1, b1, o[jd], 0, 0, 0);
            }
        }
    }

    // ---- epilogue: ctx = O / l ------------------------------------------
    #pragma unroll
    for (int r = 0; r < 4; ++r) {
        const float inv = 1.f / zl[r];
        const int sq = rmin + g * 4 + r;
        #pragma unroll
        for (int jd = 0; jd < 4; ++jd)
            ctx[hb + (size_t)sq * DM + jd * 16 + l15] =
                __float2bfloat16(o[jd][r] * inv);
    }
}

// ---------------------------------------------------------------------------
extern "C" void kernel_launch(void* const* d_in, const int* in_sizes, int n_in,
                              void* d_out, int out_size, void* d_ws, size_t ws_size,
                              hipStream_t stream) {
    const int M = 4 * SEQ;   // 8192

    // size-based input mapping
    int xi = 0, wi[4] = {-1, -1, -1, -1}, bi[4] = {-1, -1, -1, -1};
    int nw = 0, nb = 0;
    for (int i = 0; i < n_in; ++i) {
        if (in_sizes[i] == 4 * SEQ * DM) xi = i;
        else if (in_sizes[i] == DM * DM && nw < 4) wi[nw++] = i;
        else if (in_sizes[i] == DM && nb < 4) bi[nb++] = i;
    }
    if (nw < 4 || nb < 4) {
        const int wOff = n_in - 8;
        for (int j = 0; j < 4; ++j) { wi[j] = wOff + 2 * j; bi[j] = wOff + 2 * j + 1; }
    }
    const void* x  = d_in[xi];
    const void* W[4]  = {d_in[wi[0]], d_in[wi[1]], d_in[wi[2]], d_in[wi[3]]};
    const void* Bs[4] = {d_in[bi[0]], d_in[bi[1]], d_in[bi[2]], d_in[bi[3]]};

    // ws: q | kk | vt | flag [| wob if room]. ctx aliases q.
    const size_t mat = (size_t)M * DM;
    const size_t base = 3 * mat * sizeof(__hip_bfloat16);   // 50.33 MB
    __hip_bfloat16* q   = (__hip_bfloat16*)d_ws;
    __hip_bfloat16* kk  = q + mat;
    __hip_bfloat16* vt  = kk + mat;
    __hip_bfloat16* ctx = q;
    int* flag = (int*)((char*)d_ws + base);

    // Fused-Wo path: wob lives in ws after flag (256B aligned) if it fits.
    __hip_bfloat16* wob2 = (__hip_bfloat16*)((char*)d_ws + base + 256);
    const bool fuseW3 = ws_size >= base + 256 + sizeof(__hip_bfloat16) * DM * DM;

    // d_out scratch: xb (16.78 MB) + wb (6.29 MB); both dead before gemm_out.
    __hip_bfloat16* xb  = (__hip_bfloat16*)d_out;
    __hip_bfloat16* wb  = xb + mat;
    __hip_bfloat16* wob = kk;            // fallback Wo location (after attn)

    // fused detect + x cast + W0-2 casts (+W3 if workspace allows)
    prep_cast<<<dim3(8192 + (fuseW3 ? 4 : 3) * 1024), 256, 0, stream>>>(
        x, W[0], W[1], W[2], W[3], xb, wb, wob2, flag);

    gemm_qkv<<<dim3(M / 128, 24), 256, 0, stream>>>(
        xb, wb, Bs[0], Bs[1], Bs[2], q, kk, vt, flag);

    attn_flash_mfma<<<dim3(1024), 512, 0, stream>>>(q, kk, vt, ctx);

    if (!fuseW3)
        cast4_kernel<<<dim3(DM * DM / 4 / 256), 256, 0, stream>>>(
            W[3], wob, flag, DM * DM / 4);

    gemm_out<<<dim3(M / 128, DM / 128), 256, 0, stream>>>(
        ctx, fuseW3 ? wob2 : wob, Bs[3], d_out, flag);
}